// Round 1
// baseline (7779.673 us; speedup 1.0000x reference)
//
#include <hip/hip_runtime.h>
#include <hip/hip_bf16.h>

#define EPSF   1e-5f
#define DELTAF 1.2059890135352093f

#define Nn 100000
#define Ee 400000

__device__ __forceinline__ unsigned fkey(float f){
  unsigned u = __float_as_uint(f);
  return (u & 0x80000000u) ? ~u : (u | 0x80000000u);
}
__device__ __forceinline__ float funkey(unsigned k){
  return (k & 0x80000000u) ? __uint_as_float(k & 0x7fffffffu) : __uint_as_float(~k);
}

__device__ __forceinline__ float block_sum256(float v, float* sh){
  #pragma unroll
  for (int off = 32; off; off >>= 1) v += __shfl_down(v, off, 64);
  int lane = threadIdx.x & 63;
  int w = threadIdx.x >> 6;
  if (lane == 0) sh[w] = v;
  __syncthreads();
  float r = sh[0] + sh[1] + sh[2] + sh[3];
  __syncthreads();
  return r;
}

// ---------------- generic fp32 GEMM: C[m,n] = act(sum_k A[m,k]*W[n,k] + bias[n]) ----------
template<int RELU>
__global__ __launch_bounds__(256) void gemm_nt(const float* __restrict__ A,
    const float* __restrict__ W, const float* __restrict__ bias,
    float* __restrict__ C, int M, int N, int K){
  __shared__ float As[64][20];
  __shared__ float Ws[64][20];
  int t = threadIdx.x;
  int ty = t >> 4, tx = t & 15;
  int lr = t >> 2, lq = t & 3;
  int mb = blockIdx.x, nb = blockIdx.y;
  float acc[4][4] = {};
  int arow = mb*64 + lr; if (arow > M-1) arow = M-1;
  const float* Ap = A + (size_t)arow * K;
  const float* Wp = W + (size_t)(nb*64 + lr) * K;
  int nch = K >> 4;
  for (int ch = 0; ch < nch; ch++){
    float4 av = *(const float4*)(Ap + ch*16 + lq*4);
    float4 wv = *(const float4*)(Wp + ch*16 + lq*4);
    __syncthreads();
    *(float4*)&As[lr][lq*4] = av;
    *(float4*)&Ws[lr][lq*4] = wv;
    __syncthreads();
    #pragma unroll
    for (int kk = 0; kk < 16; kk++){
      float a0=As[ty*4+0][kk], a1=As[ty*4+1][kk], a2=As[ty*4+2][kk], a3=As[ty*4+3][kk];
      float w0=Ws[tx*4+0][kk], w1=Ws[tx*4+1][kk], w2=Ws[tx*4+2][kk], w3=Ws[tx*4+3][kk];
      acc[0][0]+=a0*w0; acc[0][1]+=a0*w1; acc[0][2]+=a0*w2; acc[0][3]+=a0*w3;
      acc[1][0]+=a1*w0; acc[1][1]+=a1*w1; acc[1][2]+=a1*w2; acc[1][3]+=a1*w3;
      acc[2][0]+=a2*w0; acc[2][1]+=a2*w1; acc[2][2]+=a2*w2; acc[2][3]+=a2*w3;
      acc[3][0]+=a3*w0; acc[3][1]+=a3*w1; acc[3][2]+=a3*w2; acc[3][3]+=a3*w3;
    }
  }
  #pragma unroll
  for (int i = 0; i < 4; i++){
    int row = mb*64 + ty*4 + i;
    if (row >= M) continue;
    #pragma unroll
    for (int j = 0; j < 4; j++){
      int col = nb*64 + tx*4 + j;
      float v = acc[i][j] + bias[col];
      if (RELU) v = fmaxf(v, 0.f);
      C[(size_t)row*N + col] = v;
    }
  }
}

// ---------------- attention: one block per (b,h), S=64, dh=32 ----------------
__global__ __launch_bounds__(256) void attn_kernel(const float* __restrict__ qkv, float* __restrict__ o){
  __shared__ float q[64][33], kk_[64][33], vv[64][33];
  __shared__ float sc[64][65];
  __shared__ float red[64][4], rowred[64];
  int t = threadIdx.x;
  int b = blockIdx.x >> 3, h = blockIdx.x & 7;
  for (int idx = t; idx < 2048; idx += 256){
    int s = idx >> 5, d = idx & 31;
    const float* base = qkv + (size_t)(b*64 + s)*768 + h*32 + d;
    q[s][d]   = base[0];
    kk_[s][d] = base[256];
    vv[s][d]  = base[512];
  }
  __syncthreads();
  for (int idx = t; idx < 4096; idx += 256){
    int i = idx >> 6, j = idx & 63;
    float a = 0.f;
    #pragma unroll
    for (int d = 0; d < 32; d++) a += q[i][d]*kk_[j][d];
    sc[i][j] = a * 0.17677669529663687f;   // 1/sqrt(32)
  }
  __syncthreads();
  int r = t >> 2, p = t & 3;
  float m = -1e30f;
  #pragma unroll
  for (int j = 0; j < 16; j++) m = fmaxf(m, sc[r][p*16+j]);
  red[r][p] = m;
  __syncthreads();
  if (p == 0) rowred[r] = fmaxf(fmaxf(red[r][0],red[r][1]), fmaxf(red[r][2],red[r][3]));
  __syncthreads();
  float mx = rowred[r];
  float ssum = 0.f;
  #pragma unroll
  for (int j = 0; j < 16; j++){ float e = __expf(sc[r][p*16+j] - mx); sc[r][p*16+j] = e; ssum += e; }
  red[r][p] = ssum;
  __syncthreads();
  if (p == 0) rowred[r] = red[r][0]+red[r][1]+red[r][2]+red[r][3];
  __syncthreads();
  float inv = 1.f / rowred[r];
  #pragma unroll
  for (int j = 0; j < 16; j++) sc[r][p*16+j] *= inv;
  __syncthreads();
  for (int idx = t; idx < 2048; idx += 256){
    int i = idx >> 5, d = idx & 31;
    float a = 0.f;
    #pragma unroll
    for (int j = 0; j < 64; j++) a += sc[i][j]*vv[j][d];
    o[(size_t)(b*64 + i)*256 + h*32 + d] = a;
  }
}

// ---------------- h1 = LN(x + y) ----------------
__global__ __launch_bounds__(256) void add_ln(const float* __restrict__ x, const float* __restrict__ y,
    const float* __restrict__ g, const float* __restrict__ be, float* __restrict__ out){
  __shared__ float sh[4];
  int m = blockIdx.x, t = threadIdx.x;
  size_t idx = (size_t)m*256 + t;
  float v = x[idx] + y[idx];
  float mean = block_sum256(v, sh) * (1.f/256.f);
  float d = v - mean;
  float var = block_sum256(d*d, sh) * (1.f/256.f);
  out[idx] = g[t]*d*rsqrtf(var + EPSF) + be[t];
}

// ---------------- x_tab_out = LN(LN(h1 + ffn2)) ----------------
__global__ __launch_bounds__(256) void final_tab(const float* __restrict__ h1v, const float* __restrict__ f2,
    const float* __restrict__ g2, const float* __restrict__ b2v,
    const float* __restrict__ g3, const float* __restrict__ b3v, float* __restrict__ out){
  __shared__ float sh[4];
  int m = blockIdx.x, t = threadIdx.x;
  size_t idx = (size_t)m*256 + t;
  float v = h1v[idx] + f2[idx];
  float mean = block_sum256(v, sh) * (1.f/256.f);
  float d = v - mean;
  float var = block_sum256(d*d, sh) * (1.f/256.f);
  float h2 = g2[t]*d*rsqrtf(var + EPSF) + b2v[t];
  float mean2 = block_sum256(h2, sh) * (1.f/256.f);
  float d2 = h2 - mean2;
  float var2 = block_sum256(d2*d2, sh) * (1.f/256.f);
  out[idx] = g3[t]*d2*rsqrtf(var2 + EPSF) + b3v[t];
}

// ---------------- fold edge encoder into pre_nn:  Wfull[128][384], bfull[128] -------------
__global__ __launch_bounds__(128) void fuse_pre(const float* __restrict__ encw, const float* __restrict__ encb,
    const float* __restrict__ prew, const float* __restrict__ preb,
    float* __restrict__ Wf, float* __restrict__ bf){
  int nrow = blockIdx.x;
  int j = threadIdx.x;
  Wf[nrow*384 + j]       = prew[nrow*384 + j];
  Wf[nrow*384 + 128 + j] = prew[nrow*384 + 128 + j];
  float a = 0.f;
  for (int u = 0; u < 128; u++) a += prew[nrow*384 + 256 + u] * encw[u*128 + j];
  Wf[nrow*384 + 256 + j] = a;
  if (j == 0){
    float bb = preb[nrow];
    for (int u = 0; u < 128; u++) bb += prew[nrow*384 + 256 + u] * encb[u];
    bf[nrow] = bb;
  }
}

__global__ void init_agg(float* sum, float* sumsq, unsigned* maxk, unsigned* mink,
                         float* cnt, float* stats){
  int i = blockIdx.x*256 + threadIdx.x;   // grid covers exactly 12,800,000
  sum[i] = 0.f; sumsq[i] = 0.f; maxk[i] = 0u; mink[i] = 0xFFFFFFFFu;
  if (i < Nn)  cnt[i] = 0.f;
  if (i < 256) stats[i] = 0.f;
}

__global__ void edge_count(const int* __restrict__ ei, float* __restrict__ cnt){
  int i = blockIdx.x*256 + threadIdx.x;
  if (i < Ee) atomicAdd(&cnt[ei[Ee + i]], 1.0f);
}

// ---------------- edge GEMM (K=384, gathered A) + atomic aggregation epilogue ------------
__global__ __launch_bounds__(256) void edge_gemm_agg(
    const float* __restrict__ xg, const float* __restrict__ ea, const int* __restrict__ ei,
    const float* __restrict__ Wf, const float* __restrict__ bf,
    float* __restrict__ sum, float* __restrict__ sumsq,
    unsigned* __restrict__ maxk, unsigned* __restrict__ mink){
  __shared__ float As[64][20], Ws[64][20];
  __shared__ int dsts[64], srcs[64];
  int t = threadIdx.x;
  int eb = blockIdx.x, nb = blockIdx.y;
  if (t < 64){ int e = eb*64 + t; srcs[t] = ei[e]; dsts[t] = ei[Ee + e]; }
  int ty = t >> 4, tx = t & 15, lr = t >> 2, lq = t & 3;
  float acc[4][4] = {};
  const float* Wp = Wf + (size_t)(nb*64 + lr)*384;
  __syncthreads();
  for (int ch = 0; ch < 24; ch++){
    int k = ch*16 + lq*4;
    float4 av;
    if (ch < 8)       av = *(const float4*)(xg + (size_t)dsts[lr]*128 + k);
    else if (ch < 16) av = *(const float4*)(xg + (size_t)srcs[lr]*128 + (k - 128));
    else              av = *(const float4*)(ea + (size_t)(eb*64 + lr)*128 + (k - 256));
    float4 wv = *(const float4*)(Wp + k);
    __syncthreads();
    *(float4*)&As[lr][lq*4] = av;
    *(float4*)&Ws[lr][lq*4] = wv;
    __syncthreads();
    #pragma unroll
    for (int kk = 0; kk < 16; kk++){
      float a0=As[ty*4+0][kk], a1=As[ty*4+1][kk], a2=As[ty*4+2][kk], a3=As[ty*4+3][kk];
      float w0=Ws[tx*4+0][kk], w1=Ws[tx*4+1][kk], w2=Ws[tx*4+2][kk], w3=Ws[tx*4+3][kk];
      acc[0][0]+=a0*w0; acc[0][1]+=a0*w1; acc[0][2]+=a0*w2; acc[0][3]+=a0*w3;
      acc[1][0]+=a1*w0; acc[1][1]+=a1*w1; acc[1][2]+=a1*w2; acc[1][3]+=a1*w3;
      acc[2][0]+=a2*w0; acc[2][1]+=a2*w1; acc[2][2]+=a2*w2; acc[2][3]+=a2*w3;
      acc[3][0]+=a3*w0; acc[3][1]+=a3*w1; acc[3][2]+=a3*w2; acc[3][3]+=a3*w3;
    }
  }
  #pragma unroll
  for (int i = 0; i < 4; i++){
    int d = dsts[ty*4 + i];
    #pragma unroll
    for (int j = 0; j < 4; j++){
      int f = nb*64 + tx*4 + j;
      float v = acc[i][j] + bf[f];
      int idx = d*128 + f;
      atomicAdd(&sum[idx], v);
      atomicAdd(&sumsq[idx], v*v);
      atomicMax(&maxk[idx], fkey(v));
      atomicMin(&mink[idx], fkey(v));
    }
  }
}

// ---------------- build Agg[N][512] = [mean|max|min|std], amp[N], att[N] ------------------
__global__ void agg_build(const float* __restrict__ sum, const float* __restrict__ sumsq,
    const unsigned* __restrict__ maxk, const unsigned* __restrict__ mink,
    const float* __restrict__ cnt, float* __restrict__ Agg,
    float* __restrict__ ampv, float* __restrict__ attv){
  int i = blockIdx.x*256 + threadIdx.x;
  if (i >= Nn*128) return;
  int n = i >> 7, f = i & 127;
  float c = cnt[n];
  float denom = fmaxf(c, 1.f);
  float me = sum[i] / denom;
  float m2 = sumsq[i] / denom;
  float sd = sqrtf(fmaxf(m2 - me*me, 0.f) + EPSF);
  bool has = c > 0.f;
  float mx = has ? funkey(maxk[i]) : 0.f;
  float mn = has ? funkey(mink[i]) : 0.f;
  float* a = Agg + (size_t)n*512;
  a[f] = me; a[128 + f] = mx; a[256 + f] = mn; a[384 + f] = sd;
  if (f == 0){
    float l = logf(denom + 1.f);
    ampv[n] = l * (1.f/DELTAF);
    attv[n] = DELTAF / l;
  }
}

// ---------------- post_nn GEMM (K=1664, A gathered from x|agg|agg*amp|agg*att) ------------
__global__ __launch_bounds__(256) void node_gemm(
    const float* __restrict__ xg, const float* __restrict__ Agg,
    const float* __restrict__ ampv, const float* __restrict__ attv,
    const float* __restrict__ Wp_, const float* __restrict__ bp,
    float* __restrict__ out){
  __shared__ float As[64][20], Ws[64][20];
  __shared__ float amps[64], atts[64];
  int t = threadIdx.x, mb = blockIdx.x, nb = blockIdx.y;
  if (t < 64){ int n = mb*64 + t; if (n > Nn-1) n = Nn-1; amps[t] = ampv[n]; atts[t] = attv[n]; }
  int ty = t >> 4, tx = t & 15, lr = t >> 2, lq = t & 3;
  float acc[4][4] = {};
  int n = mb*64 + lr; if (n > Nn-1) n = Nn-1;
  const float* xrow = xg  + (size_t)n*128;
  const float* arow = Agg + (size_t)n*512;
  const float* wrow = Wp_ + (size_t)(nb*64 + lr)*1664;
  __syncthreads();
  for (int ch = 0; ch < 104; ch++){
    int k = ch*16 + lq*4;
    float4 av; float scl = 1.f;
    if (ch < 8)        av = *(const float4*)(xrow + k);
    else if (ch < 40)  av = *(const float4*)(arow + (k - 128));
    else if (ch < 72){ av = *(const float4*)(arow + (k - 640));  scl = amps[lr]; }
    else             { av = *(const float4*)(arow + (k - 1152)); scl = atts[lr]; }
    float4 wv = *(const float4*)(wrow + k);
    __syncthreads();
    As[lr][lq*4+0] = av.x*scl; As[lr][lq*4+1] = av.y*scl;
    As[lr][lq*4+2] = av.z*scl; As[lr][lq*4+3] = av.w*scl;
    *(float4*)&Ws[lr][lq*4] = wv;
    __syncthreads();
    #pragma unroll
    for (int kk = 0; kk < 16; kk++){
      float a0=As[ty*4+0][kk], a1=As[ty*4+1][kk], a2=As[ty*4+2][kk], a3=As[ty*4+3][kk];
      float w0=Ws[tx*4+0][kk], w1=Ws[tx*4+1][kk], w2=Ws[tx*4+2][kk], w3=Ws[tx*4+3][kk];
      acc[0][0]+=a0*w0; acc[0][1]+=a0*w1; acc[0][2]+=a0*w2; acc[0][3]+=a0*w3;
      acc[1][0]+=a1*w0; acc[1][1]+=a1*w1; acc[1][2]+=a1*w2; acc[1][3]+=a1*w3;
      acc[2][0]+=a2*w0; acc[2][1]+=a2*w1; acc[2][2]+=a2*w2; acc[2][3]+=a2*w3;
      acc[3][0]+=a3*w0; acc[3][1]+=a3*w1; acc[3][2]+=a3*w2; acc[3][3]+=a3*w3;
    }
  }
  #pragma unroll
  for (int i = 0; i < 4; i++){
    int row = mb*64 + ty*4 + i;
    if (row >= Nn) continue;
    #pragma unroll
    for (int j = 0; j < 4; j++){
      int f = nb*64 + tx*4 + j;
      out[(size_t)row*128 + f] = acc[i][j] + bp[f];
    }
  }
}

// ---------------- BN column stats: stats[0:128]=sum, [128:256]=sumsq ----------------------
__global__ __launch_bounds__(256) void bn_stats(const float* __restrict__ x, float* __restrict__ stats){
  __shared__ float ls[128], lq[128];
  int t = threadIdx.x;
  if (t < 128){ ls[t] = 0.f; lq[t] = 0.f; }
  __syncthreads();
  const int total4 = (Nn*128)/4;
  float s0=0,s1=0,s2=0,s3=0,q0=0,q1=0,q2=0,q3=0;
  for (int i = blockIdx.x*256 + t; i < total4; i += gridDim.x*256){
    float4 v = ((const float4*)x)[i];
    s0 += v.x; q0 += v.x*v.x;
    s1 += v.y; q1 += v.y*v.y;
    s2 += v.z; q2 += v.z*v.z;
    s3 += v.w; q3 += v.w*v.w;
  }
  int f0 = (t & 31)*4;   // grid*256*4 is a multiple of 128 -> feature fixed per thread
  atomicAdd(&ls[f0+0], s0); atomicAdd(&ls[f0+1], s1);
  atomicAdd(&ls[f0+2], s2); atomicAdd(&ls[f0+3], s3);
  atomicAdd(&lq[f0+0], q0); atomicAdd(&lq[f0+1], q1);
  atomicAdd(&lq[f0+2], q2); atomicAdd(&lq[f0+3], q3);
  __syncthreads();
  if (t < 128){
    atomicAdd(&stats[t], ls[t]);
    atomicAdd(&stats[128 + t], lq[t]);
  }
}

// ---------------- x_gnn_out = (x_gnn + relu(BN(out2))) * 0.5 ----------------
__global__ void gnn_final(const float* __restrict__ out2, const float* __restrict__ xg,
    const float* __restrict__ bng, const float* __restrict__ bnb,
    const float* __restrict__ stats, float* __restrict__ out){
  int i = blockIdx.x*256 + threadIdx.x;
  if (i >= Nn*128) return;
  int f = i & 127;
  float mu  = stats[f] * (1.0f/Nn);
  float var = stats[128 + f] * (1.0f/Nn) - mu*mu;
  float y = bng[f]*(out2[i] - mu)*rsqrtf(var + EPSF) + bnb[f];
  out[i] = (xg[i] + fmaxf(y, 0.f)) * 0.5f;
}

extern "C" void kernel_launch(void* const* d_in, const int* in_sizes, int n_in,
                              void* d_out, int out_size, void* d_ws, size_t ws_size,
                              hipStream_t stream){
  const float* x_tab = (const float*)d_in[0];
  const float* x_gnn = (const float*)d_in[1];
  const int*   eidx  = (const int*)d_in[2];
  const float* eattr = (const float*)d_in[3];
  const float* in_w  = (const float*)d_in[4];  const float* in_b  = (const float*)d_in[5];
  const float* ow    = (const float*)d_in[6];  const float* ob    = (const float*)d_in[7];
  const float* l1w   = (const float*)d_in[8];  const float* l1b   = (const float*)d_in[9];
  const float* l2w   = (const float*)d_in[10]; const float* l2b   = (const float*)d_in[11];
  const float* ln1g  = (const float*)d_in[12]; const float* ln1b  = (const float*)d_in[13];
  const float* ln2g  = (const float*)d_in[14]; const float* ln2b  = (const float*)d_in[15];
  const float* tng   = (const float*)d_in[16]; const float* tnb   = (const float*)d_in[17];
  const float* encw  = (const float*)d_in[18]; const float* encb  = (const float*)d_in[19];
  const float* prew  = (const float*)d_in[20]; const float* preb  = (const float*)d_in[21];
  const float* postw = (const float*)d_in[22]; const float* postb = (const float*)d_in[23];
  const float* lpw   = (const float*)d_in[24]; const float* lpb   = (const float*)d_in[25];
  const float* bng   = (const float*)d_in[26]; const float* bnb   = (const float*)d_in[27];

  float* ws = (float*)d_ws;
  float* r0 = ws;                      // 67,108,864 floats (qkv -> ffn1 -> gnn scratch)
  float* b1 = ws + 67108864;           // 16,777,216
  float* b2 = b1 + 16777216;           // 16,777,216
  float* b3 = b2 + 16777216;           // 51,200,000 (Agg)
  // gnn scratch inside r0 (only used after tab phase is done with r0)
  float*    gsum   = r0;
  float*    gsumsq = r0 + 12800000;
  unsigned* gmaxk  = (unsigned*)(r0 + 25600000);
  unsigned* gmink  = (unsigned*)(r0 + 38400000);
  float*    gcnt   = r0 + 51200000;
  float*    gamp   = r0 + 51300000;
  float*    gatt   = r0 + 51400000;
  float*    gstats = r0 + 51500000;
  float*    gWf    = r0 + 51500256;
  float*    gbf    = r0 + 51549408;

  float* out_tab   = (float*)d_out;
  float* out_gnn   = out_tab + 16777216;
  float* out_eattr = out_gnn + 12800000;

  // ---- tab branch ----
  gemm_nt<0><<<dim3(1024,12),256,0,stream>>>(x_tab, in_w, in_b, r0, 65536, 768, 256);   // qkv
  attn_kernel<<<8192,256,0,stream>>>(r0, b1);                                           // attn -> o
  gemm_nt<0><<<dim3(1024,4),256,0,stream>>>(b1, ow, ob, b2, 65536, 256, 256);           // out proj
  add_ln<<<65536,256,0,stream>>>(x_tab, b2, ln1g, ln1b, b1);                            // h1
  gemm_nt<1><<<dim3(1024,16),256,0,stream>>>(b1, l1w, l1b, r0, 65536, 1024, 256);       // ffn1(relu)
  gemm_nt<0><<<dim3(1024,4),256,0,stream>>>(r0, l2w, l2b, b2, 65536, 256, 1024);        // ffn2
  final_tab<<<65536,256,0,stream>>>(b1, b2, ln2g, ln2b, tng, tnb, out_tab);             // ln2+tabn

  // ---- gnn branch ----
  fuse_pre<<<128,128,0,stream>>>(encw, encb, prew, preb, gWf, gbf);
  init_agg<<<50000,256,0,stream>>>(gsum, gsumsq, gmaxk, gmink, gcnt, gstats);
  edge_count<<<1563,256,0,stream>>>(eidx, gcnt);
  edge_gemm_agg<<<dim3(6250,2),256,0,stream>>>(x_gnn, eattr, eidx, gWf, gbf,
                                               gsum, gsumsq, gmaxk, gmink);
  agg_build<<<50000,256,0,stream>>>(gsum, gsumsq, gmaxk, gmink, gcnt, b3, gamp, gatt);
  node_gemm<<<dim3(1563,2),256,0,stream>>>(x_gnn, b3, gamp, gatt, postw, postb, b1);
  gemm_nt<0><<<dim3(1563,2),256,0,stream>>>(b1, lpw, lpb, b2, 100000, 128, 128);        // linp
  bn_stats<<<512,256,0,stream>>>(b2, gstats);
  gnn_final<<<50000,256,0,stream>>>(b2, x_gnn, bng, bnb, gstats, out_gnn);

  hipMemcpyAsync(out_eattr, eattr, (size_t)51200000*4, hipMemcpyDeviceToDevice, stream);
}

// Round 2
// 1888.442 us; speedup vs baseline: 4.1196x; 4.1196x over previous
//
#include <hip/hip_runtime.h>
#include <hip/hip_bf16.h>

#define EPSF   1e-5f
#define DELTAF 1.2059890135352093f

#define Nn 100000
#define Ee 400000
#define NB_SCAN 391   // ceil(100000/256)

typedef __attribute__((ext_vector_type(4))) float f4;
typedef __attribute__((ext_vector_type(8))) short bfrag;

__device__ __forceinline__ int pk2(float a, float b){
  unsigned ua = __float_as_uint(a), ub = __float_as_uint(b);
  return (int)(((ua + 0x8000u) >> 16) | ((ub + 0x8000u) & 0xFFFF0000u));
}
__device__ __forceinline__ int4 pk8(f4 a, f4 b){
  return make_int4(pk2(a.x,a.y), pk2(a.z,a.w), pk2(b.x,b.y), pk2(b.z,b.w));
}

__device__ __forceinline__ float block_sum256(float v, float* sh){
  #pragma unroll
  for (int off = 32; off; off >>= 1) v += __shfl_down(v, off, 64);
  int lane = threadIdx.x & 63;
  int w = threadIdx.x >> 6;
  if (lane == 0) sh[w] = v;
  __syncthreads();
  float r = sh[0] + sh[1] + sh[2] + sh[3];
  __syncthreads();
  return r;
}

// =================== unified MFMA bf16 GEMM, tile 128x128, BK=32 ===================
// MODE 0: plain A[M][K].  MODE 1: edge gather (CSR-permuted). MODE 2: node gather.
// C[m][n] = act( sum_k A[m][k]*W[n][k] + bias[n] ), fp32 in/out, bf16 mfma.
template<int MODE, int RELU>
__global__ __launch_bounds__(256) void mgemm(
    const float* __restrict__ A, const float* __restrict__ xg,
    const float* __restrict__ ea, const int* __restrict__ ei,
    const int* __restrict__ perm, const float* __restrict__ Agg,
    const float* __restrict__ ampv, const float* __restrict__ attv,
    const float* __restrict__ W, const float* __restrict__ bias,
    float* __restrict__ C, int M, int N, int K){
  __shared__ short As[4096], Bs[4096];           // 128 rows x 32 bf16 each
  __shared__ int sE[128], sS[128], sD[128];
  __shared__ float sAmp[128], sAtt[128];
  int t = threadIdx.x;
  int nb = blockIdx.x, mb = blockIdx.y;
  if (MODE == 1){
    if (t < 128){ int e = perm[mb*128 + t]; sE[t] = e; sS[t] = ei[e]; sD[t] = ei[Ee + e]; }
    __syncthreads();
  }
  if (MODE == 2){
    if (t < 128){ int n = min(mb*128 + t, M-1); sAmp[t] = ampv[n]; sAtt[t] = attv[n]; }
    __syncthreads();
  }
  int ra = t >> 2, sg = t & 3;     // staging: rows ra and ra+64, k-seg of 8 floats
  int rb = ra + 64;
  int L = t & 63, w = t >> 6;
  int wr = w >> 1, wc = w & 1;

  const float* Aq = nullptr; const float* Ar = nullptr;
  if (MODE == 0){
    Aq = A + (size_t)min(mb*128 + ra, M-1)*K + sg*8;
    Ar = A + (size_t)min(mb*128 + rb, M-1)*K + sg*8;
  }
  const float* Wq = W + (size_t)(nb*128 + ra)*K + sg*8;
  const float* Wr = W + (size_t)(nb*128 + rb)*K + sg*8;
  short* wAa = As + ra*32 + sg*8;  short* wAb = As + rb*32 + sg*8;
  short* wBa = Bs + ra*32 + sg*8;  short* wBb = Bs + rb*32 + sg*8;
  const short* Ard = As + (wr*64 + (L&15))*32 + (L>>4)*8;
  const short* Brd = Bs + (wc*64 + (L&15))*32 + (L>>4)*8;

  f4 acc[4][4] = {};
  for (int k0 = 0; k0 < K; k0 += 32){
    const float* pa; const float* pb; float sa = 1.f, sb = 1.f;
    if (MODE == 0){ pa = Aq + k0; pb = Ar + k0; }
    else if (MODE == 1){
      int kk = k0 + sg*8;
      if (kk < 128)      { pa = xg + (size_t)sD[ra]*128 + kk;      pb = xg + (size_t)sD[rb]*128 + kk; }
      else if (kk < 256) { pa = xg + (size_t)sS[ra]*128 + kk-128;  pb = xg + (size_t)sS[rb]*128 + kk-128; }
      else               { pa = ea + (size_t)sE[ra]*128 + kk-256;  pb = ea + (size_t)sE[rb]*128 + kk-256; }
    } else {
      int kk = k0 + sg*8;
      int na = min(mb*128 + ra, M-1), nb2 = min(mb*128 + rb, M-1);
      if (kk < 128)       { pa = xg  + (size_t)na*128 + kk;        pb = xg  + (size_t)nb2*128 + kk; }
      else if (kk < 640)  { pa = Agg + (size_t)na*512 + kk-128;    pb = Agg + (size_t)nb2*512 + kk-128; }
      else if (kk < 1152) { pa = Agg + (size_t)na*512 + kk-640;    pb = Agg + (size_t)nb2*512 + kk-640;  sa = sAmp[ra]; sb = sAmp[rb]; }
      else                { pa = Agg + (size_t)na*512 + kk-1152;   pb = Agg + (size_t)nb2*512 + kk-1152; sa = sAtt[ra]; sb = sAtt[rb]; }
    }
    f4 a0 = *(const f4*)pa, a1 = *(const f4*)(pa+4);
    f4 b0 = *(const f4*)pb, b1 = *(const f4*)(pb+4);
    f4 w0 = *(const f4*)(Wq + k0), w1 = *(const f4*)(Wq + k0 + 4);
    f4 w2 = *(const f4*)(Wr + k0), w3 = *(const f4*)(Wr + k0 + 4);
    if (MODE == 2){ a0 = a0*sa; a1 = a1*sa; b0 = b0*sb; b1 = b1*sb; }
    __syncthreads();
    *(int4*)wAa = pk8(a0, a1);
    *(int4*)wAb = pk8(b0, b1);
    *(int4*)wBa = pk8(w0, w1);
    *(int4*)wBb = pk8(w2, w3);
    __syncthreads();
    bfrag af[4], bfr[4];
    #pragma unroll
    for (int i = 0; i < 4; i++){
      af[i]  = *(const bfrag*)(Ard + i*16*32);
      bfr[i] = *(const bfrag*)(Brd + i*16*32);
    }
    #pragma unroll
    for (int i = 0; i < 4; i++)
      #pragma unroll
      for (int j = 0; j < 4; j++)
        acc[i][j] = __builtin_amdgcn_mfma_f32_16x16x32_bf16(af[i], bfr[j], acc[i][j], 0, 0, 0);
  }
  int col0 = nb*128 + wc*64 + (L & 15);
  int rowb = mb*128 + wr*64 + (L >> 4)*4;
  #pragma unroll
  for (int i = 0; i < 4; i++){
    #pragma unroll
    for (int j = 0; j < 4; j++){
      int col = col0 + j*16;
      float bv = bias[col];
      #pragma unroll
      for (int rg = 0; rg < 4; rg++){
        int row = rowb + i*16 + rg;
        if (row < M){
          float v = acc[i][j][rg] + bv;
          if (RELU) v = fmaxf(v, 0.f);
          C[(size_t)row*N + col] = v;
        }
      }
    }
  }
}

// ---------------- attention: one block per (b,h), S=64, dh=32 ----------------
__global__ __launch_bounds__(256) void attn_kernel(const float* __restrict__ qkv, float* __restrict__ o){
  __shared__ float q[64][33], kk_[64][33], vv[64][33];
  __shared__ float sc[64][65];
  __shared__ float red[64][4], rowred[64];
  int t = threadIdx.x;
  int b = blockIdx.x >> 3, h = blockIdx.x & 7;
  for (int idx = t; idx < 2048; idx += 256){
    int s = idx >> 5, d = idx & 31;
    const float* base = qkv + (size_t)(b*64 + s)*768 + h*32 + d;
    q[s][d]   = base[0];
    kk_[s][d] = base[256];
    vv[s][d]  = base[512];
  }
  __syncthreads();
  for (int idx = t; idx < 4096; idx += 256){
    int i = idx >> 6, j = idx & 63;
    float a = 0.f;
    #pragma unroll
    for (int d = 0; d < 32; d++) a += q[i][d]*kk_[j][d];
    sc[i][j] = a * 0.17677669529663687f;
  }
  __syncthreads();
  int r = t >> 2, p = t & 3;
  float m = -1e30f;
  #pragma unroll
  for (int j = 0; j < 16; j++) m = fmaxf(m, sc[r][p*16+j]);
  red[r][p] = m;
  __syncthreads();
  if (p == 0) rowred[r] = fmaxf(fmaxf(red[r][0],red[r][1]), fmaxf(red[r][2],red[r][3]));
  __syncthreads();
  float mx = rowred[r];
  float ssum = 0.f;
  #pragma unroll
  for (int j = 0; j < 16; j++){ float e = __expf(sc[r][p*16+j] - mx); sc[r][p*16+j] = e; ssum += e; }
  red[r][p] = ssum;
  __syncthreads();
  if (p == 0) rowred[r] = red[r][0]+red[r][1]+red[r][2]+red[r][3];
  __syncthreads();
  float inv = 1.f / rowred[r];
  #pragma unroll
  for (int j = 0; j < 16; j++) sc[r][p*16+j] *= inv;
  __syncthreads();
  for (int idx = t; idx < 2048; idx += 256){
    int i = idx >> 5, d = idx & 31;
    float a = 0.f;
    #pragma unroll
    for (int j = 0; j < 64; j++) a += sc[i][j]*vv[j][d];
    o[(size_t)(b*64 + i)*256 + h*32 + d] = a;
  }
}

// ---------------- h1 = LN(x + y) ----------------
__global__ __launch_bounds__(256) void add_ln(const float* __restrict__ x, const float* __restrict__ y,
    const float* __restrict__ g, const float* __restrict__ be, float* __restrict__ out){
  __shared__ float sh[4];
  int m = blockIdx.x, t = threadIdx.x;
  size_t idx = (size_t)m*256 + t;
  float v = x[idx] + y[idx];
  float mean = block_sum256(v, sh) * (1.f/256.f);
  float d = v - mean;
  float var = block_sum256(d*d, sh) * (1.f/256.f);
  out[idx] = g[t]*d*rsqrtf(var + EPSF) + be[t];
}

// ---------------- x_tab_out = LN(LN(h1 + ffn2)) ----------------
__global__ __launch_bounds__(256) void final_tab(const float* __restrict__ h1v, const float* __restrict__ f2,
    const float* __restrict__ g2, const float* __restrict__ b2v,
    const float* __restrict__ g3, const float* __restrict__ b3v, float* __restrict__ out){
  __shared__ float sh[4];
  int m = blockIdx.x, t = threadIdx.x;
  size_t idx = (size_t)m*256 + t;
  float v = h1v[idx] + f2[idx];
  float mean = block_sum256(v, sh) * (1.f/256.f);
  float d = v - mean;
  float var = block_sum256(d*d, sh) * (1.f/256.f);
  float h2 = g2[t]*d*rsqrtf(var + EPSF) + b2v[t];
  float mean2 = block_sum256(h2, sh) * (1.f/256.f);
  float d2 = h2 - mean2;
  float var2 = block_sum256(d2*d2, sh) * (1.f/256.f);
  out[idx] = g3[t]*d2*rsqrtf(var2 + EPSF) + b3v[t];
}

// ---------------- fold edge encoder into pre_nn:  Wfull[128][384], bfull[128] -------------
__global__ __launch_bounds__(128) void fuse_pre(const float* __restrict__ encw, const float* __restrict__ encb,
    const float* __restrict__ prew, const float* __restrict__ preb,
    float* __restrict__ Wf, float* __restrict__ bf){
  int nrow = blockIdx.x;
  int j = threadIdx.x;
  Wf[nrow*384 + j]       = prew[nrow*384 + j];
  Wf[nrow*384 + 128 + j] = prew[nrow*384 + 128 + j];
  float a = 0.f;
  for (int u = 0; u < 128; u++) a += prew[nrow*384 + 256 + u] * encw[u*128 + j];
  Wf[nrow*384 + 256 + j] = a;
  if (j == 0){
    float bb = preb[nrow];
    for (int u = 0; u < 128; u++) bb += prew[nrow*384 + 256 + u] * encb[u];
    bf[nrow] = bb;
  }
}

// =================== CSR build ===================
__global__ void hist_kernel(const int* __restrict__ ei, int* __restrict__ cnt){
  int i = blockIdx.x*256 + threadIdx.x;
  if (i < Ee) atomicAdd(&cnt[ei[Ee + i]], 1);
}

__global__ __launch_bounds__(256) void scan1(const int* __restrict__ cnt,
    int* __restrict__ incl, int* __restrict__ bsum){
  __shared__ int sh[256];
  int t = threadIdx.x, i = blockIdx.x*256 + t;
  int v = (i < Nn) ? cnt[i] : 0;
  sh[t] = v; __syncthreads();
  for (int off = 1; off < 256; off <<= 1){
    int x = (t >= off) ? sh[t-off] : 0;
    __syncthreads();
    sh[t] += x;
    __syncthreads();
  }
  if (i < Nn) incl[i] = sh[t];
  if (t == 255) bsum[blockIdx.x] = sh[255];
}

__global__ void scan2(int* __restrict__ bsum){
  if (threadIdx.x == 0){
    int run = 0;
    for (int b = 0; b < NB_SCAN; b++){ int v = bsum[b]; bsum[b] = run; run += v; }
  }
}

__global__ void scan3(const int* __restrict__ incl, const int* __restrict__ cnt,
    const int* __restrict__ bsum, int* __restrict__ rs, int* __restrict__ cur){
  int i = blockIdx.x*256 + threadIdx.x;
  if (i < Nn){
    int v = incl[i] - cnt[i] + bsum[blockIdx.x];
    rs[i] = v; cur[i] = v;
  }
  if (i == 0) rs[Nn] = Ee;
}

__global__ void scatter_k(const int* __restrict__ ei, int* __restrict__ cur, int* __restrict__ perm){
  int e = blockIdx.x*256 + threadIdx.x;
  if (e < Ee){
    int d = ei[Ee + e];
    int p = atomicAdd(&cur[d], 1);
    perm[p] = e;
  }
}

// =================== per-node segment reduce: Agg[N][512]=[mean|max|min|std] ===================
__global__ __launch_bounds__(128) void seg_reduce(const float* __restrict__ H, const int* __restrict__ rs,
    float* __restrict__ Agg, float* __restrict__ ampv, float* __restrict__ attv){
  int n = blockIdx.x, f = threadIdx.x;
  int s = rs[n], e = rs[n+1];
  float sm = 0.f, sq = 0.f, mx = -1e30f, mn = 1e30f;
  for (int r = s; r < e; r++){
    float v = H[(size_t)r*128 + f];
    sm += v; sq += v*v; mx = fmaxf(mx, v); mn = fminf(mn, v);
  }
  int deg = e - s;
  float denom = fmaxf((float)deg, 1.f);
  float mean = sm/denom, m2 = sq/denom;
  float sd = sqrtf(fmaxf(m2 - mean*mean, 0.f) + EPSF);
  if (deg == 0){ mx = 0.f; mn = 0.f; }
  float* a = Agg + (size_t)n*512;
  a[f] = mean; a[128+f] = mx; a[256+f] = mn; a[384+f] = sd;
  if (f == 0){
    float l = logf(denom + 1.f);
    ampv[n] = l * (1.f/DELTAF);
    attv[n] = DELTAF / l;
  }
}

// ---------------- BN column stats ----------------
__global__ __launch_bounds__(256) void bn_stats(const float* __restrict__ x, float* __restrict__ stats){
  __shared__ float ls[128], lq[128];
  int t = threadIdx.x;
  if (t < 128){ ls[t] = 0.f; lq[t] = 0.f; }
  __syncthreads();
  const int total4 = (Nn*128)/4;
  float s0=0,s1=0,s2=0,s3=0,q0=0,q1=0,q2=0,q3=0;
  for (int i = blockIdx.x*256 + t; i < total4; i += gridDim.x*256){
    float4 v = ((const float4*)x)[i];
    s0 += v.x; q0 += v.x*v.x;
    s1 += v.y; q1 += v.y*v.y;
    s2 += v.z; q2 += v.z*v.z;
    s3 += v.w; q3 += v.w*v.w;
  }
  int f0 = (t & 31)*4;
  atomicAdd(&ls[f0+0], s0); atomicAdd(&ls[f0+1], s1);
  atomicAdd(&ls[f0+2], s2); atomicAdd(&ls[f0+3], s3);
  atomicAdd(&lq[f0+0], q0); atomicAdd(&lq[f0+1], q1);
  atomicAdd(&lq[f0+2], q2); atomicAdd(&lq[f0+3], q3);
  __syncthreads();
  if (t < 128){
    atomicAdd(&stats[t], ls[t]);
    atomicAdd(&stats[128 + t], lq[t]);
  }
}

__global__ void gnn_final(const float* __restrict__ out2, const float* __restrict__ xg,
    const float* __restrict__ bng, const float* __restrict__ bnb,
    const float* __restrict__ stats, float* __restrict__ out){
  int i = blockIdx.x*256 + threadIdx.x;
  if (i >= Nn*128) return;
  int f = i & 127;
  float mu  = stats[f] * (1.0f/Nn);
  float var = stats[128 + f] * (1.0f/Nn) - mu*mu;
  float y = bng[f]*(out2[i] - mu)*rsqrtf(var + EPSF) + bnb[f];
  out[i] = (xg[i] + fmaxf(y, 0.f)) * 0.5f;
}

extern "C" void kernel_launch(void* const* d_in, const int* in_sizes, int n_in,
                              void* d_out, int out_size, void* d_ws, size_t ws_size,
                              hipStream_t stream){
  const float* x_tab = (const float*)d_in[0];
  const float* x_gnn = (const float*)d_in[1];
  const int*   eidx  = (const int*)d_in[2];
  const float* eattr = (const float*)d_in[3];
  const float* in_w  = (const float*)d_in[4];  const float* in_b  = (const float*)d_in[5];
  const float* ow    = (const float*)d_in[6];  const float* ob    = (const float*)d_in[7];
  const float* l1w   = (const float*)d_in[8];  const float* l1b   = (const float*)d_in[9];
  const float* l2w   = (const float*)d_in[10]; const float* l2b   = (const float*)d_in[11];
  const float* ln1g  = (const float*)d_in[12]; const float* ln1b  = (const float*)d_in[13];
  const float* ln2g  = (const float*)d_in[14]; const float* ln2b  = (const float*)d_in[15];
  const float* tng   = (const float*)d_in[16]; const float* tnb   = (const float*)d_in[17];
  const float* encw  = (const float*)d_in[18]; const float* encb  = (const float*)d_in[19];
  const float* prew  = (const float*)d_in[20]; const float* preb  = (const float*)d_in[21];
  const float* postw = (const float*)d_in[22]; const float* postb = (const float*)d_in[23];
  const float* lpw   = (const float*)d_in[24]; const float* lpb   = (const float*)d_in[25];
  const float* bng   = (const float*)d_in[26]; const float* bnb   = (const float*)d_in[27];

  float* ws = (float*)d_ws;
  float* r0 = ws;                      // 67,108,864 floats: qkv out / ffn1 out / gnn scratch
  float* b1 = ws + 67108864;           // 16,777,216
  float* b2 = b1 + 16777216;           // 16,777,216
  float* b3 = b2 + 16777216;           // 51,200,000 (Agg)

  // gnn-phase scratch inside r0 (tab phase done with r0 by then)
  float* H    = r0;                    // 51,200,000 floats (sorted edge features)
  float* tail = r0 + 51200000;
  int* cnt  = (int*)tail;              // 100,000
  int* incl = cnt + 100000;            // 100,000
  int* bsum = incl + 100000;           // 512
  int* rs   = bsum + 512;              // 100,001
  int* cur  = rs + 100001;             // 100,000
  int* perm = cur + 100000;            // 400,000
  float* gWf    = (float*)(perm + 400000);   // 49,152
  float* gbf    = gWf + 49152;               // 128
  float* gamp   = gbf + 128;                 // 100,000
  float* gatt   = gamp + 100000;             // 100,000
  float* gstats = gatt + 100000;             // 256

  float* out_tab   = (float*)d_out;
  float* out_gnn   = out_tab + 16777216;
  float* out_eattr = out_gnn + 12800000;

  const float* Z = nullptr; const int* ZI = nullptr;

  // ---- tab branch ----
  mgemm<0,0><<<dim3(6,512),256,0,stream>>>(x_tab, Z,Z,ZI,ZI,Z,Z,Z, in_w, in_b, r0, 65536, 768, 256);
  attn_kernel<<<8192,256,0,stream>>>(r0, b1);
  mgemm<0,0><<<dim3(2,512),256,0,stream>>>(b1, Z,Z,ZI,ZI,Z,Z,Z, ow, ob, b2, 65536, 256, 256);
  add_ln<<<65536,256,0,stream>>>(x_tab, b2, ln1g, ln1b, b1);
  mgemm<0,1><<<dim3(8,512),256,0,stream>>>(b1, Z,Z,ZI,ZI,Z,Z,Z, l1w, l1b, r0, 65536, 1024, 256);
  mgemm<0,0><<<dim3(2,512),256,0,stream>>>(r0, Z,Z,ZI,ZI,Z,Z,Z, l2w, l2b, b2, 65536, 256, 1024);
  final_tab<<<65536,256,0,stream>>>(b1, b2, ln2g, ln2b, tng, tnb, out_tab);

  // ---- gnn branch ----
  fuse_pre<<<128,128,0,stream>>>(encw, encb, prew, preb, gWf, gbf);
  hipMemsetAsync(cnt, 0, 100000*sizeof(int), stream);
  hipMemsetAsync(gstats, 0, 256*sizeof(float), stream);
  hist_kernel<<<1563,256,0,stream>>>(eidx, cnt);
  scan1<<<NB_SCAN,256,0,stream>>>(cnt, incl, bsum);
  scan2<<<1,64,0,stream>>>(bsum);
  scan3<<<NB_SCAN,256,0,stream>>>(incl, cnt, bsum, rs, cur);
  scatter_k<<<1563,256,0,stream>>>(eidx, cur, perm);
  // edge GEMM -> H (sorted by dst), K=384 fused [x_dst|x_src|enc(edge_attr)]
  mgemm<1,0><<<dim3(1,3125),256,0,stream>>>(Z, x_gnn, eattr, eidx, perm, Z,Z,Z, gWf, gbf, H, Ee, 128, 384);
  seg_reduce<<<100000,128,0,stream>>>(H, rs, b3, gamp, gatt);
  // post_nn GEMM, K=1664 gathered [x|agg|agg*amp|agg*att]
  mgemm<2,0><<<dim3(1,782),256,0,stream>>>(Z, x_gnn, Z, ZI, ZI, b3, gamp, gatt, postw, postb, b1, Nn, 128, 1664);
  mgemm<0,0><<<dim3(1,782),256,0,stream>>>(b1, Z,Z,ZI,ZI,Z,Z,Z, lpw, lpb, b2, Nn, 128, 128);
  bn_stats<<<512,256,0,stream>>>(b2, gstats);
  gnn_final<<<50000,256,0,stream>>>(b2, x_gnn, bng, bnb, gstats, out_gnn);

  hipMemcpyAsync(out_eattr, eattr, (size_t)51200000*4, hipMemcpyDeviceToDevice, stream);
}